// Round 7
// baseline (93.591 us; speedup 1.0000x reference)
//
#include <hip/hip_runtime.h>
#include <hip/hip_bf16.h>

#define D_ 256
#define HW_ 1024

typedef short short4v __attribute__((ext_vector_type(4)));
typedef short short8 __attribute__((ext_vector_type(8)));
typedef float float4v __attribute__((ext_vector_type(4)));

__device__ __forceinline__ unsigned short f2bf(float f) {
  unsigned u = __builtin_bit_cast(unsigned, f);
  return (unsigned short)((u + 0x7fffu + ((u >> 16) & 1u)) >> 16);
}
__device__ __forceinline__ float bf2f(unsigned short h) {
  return __builtin_bit_cast(float, ((unsigned)h) << 16);
}

__device__ __forceinline__ void async16(void* lds, const void* g) {
  __builtin_amdgcn_global_load_lds(
      (__attribute__((address_space(1))) const unsigned int*)g,
      (__attribute__((address_space(3))) unsigned int*)lds, 16, 0, 0);
}

// ---- prep: cnorm + bf16(-2c) swizzled image, 64-code chunks (32KB each) ----
// chunk=k>>6 (stride 16384 ushorts = 32KB), row=k&63 (512B rows);
// ushort for feature d at d ^ ((row&15)<<4)
__global__ __launch_bounds__(256) void vq_prep(const float* __restrict__ cb,
                                               unsigned short* __restrict__ cbimg,
                                               float* __restrict__ cnorm) {
  int k = blockIdx.x;   // 0..1023
  int t = threadIdx.x;  // 0..255 (= feature d)
  float c = cb[k * D_ + t];
  float s = c * c;
#pragma unroll
  for (int off = 1; off < 64; off <<= 1) s += __shfl_xor(s, off, 64);
  __shared__ float wsum[4];
  if ((t & 63) == 0) wsum[t >> 6] = s;
  __syncthreads();
  if (t == 0) cnorm[k] = wsum[0] + wsum[1] + wsum[2] + wsum[3];
  int row = k & 63, chunk = k >> 6;
  cbimg[chunk * 16384 + row * 256 + (t ^ ((row & 15) << 4))] = f2bf(-2.0f * c);
}

// ---- main: stage pts + stream codebook + argmin + loss + cooperative gather ----
// 512 blocks x 256 thr (4 waves), 128 pts/block.
// Loop: pg=w>>1 owns 64 pts (pf=4), ch=w&1 covers 32 of 64 codes (af=2) -> 1:4 reuse.
__global__ __launch_bounds__(256) void vq_main(const float* __restrict__ lat,
                                               const short8* __restrict__ cbimg,
                                               const float* __restrict__ cnorm,
                                               const float* __restrict__ cb,
                                               float* __restrict__ out,
                                               float* __restrict__ part) {
  __shared__ short8 dbuf[2][2048];   // 2 x 32KB: pt tiles / cb dbuf / gather tiles
  __shared__ float cnorm_s[1024];    // 4KB
  __shared__ float mergeD[128];
  __shared__ int mergeI[128];
  __shared__ int idx_s[128];

  const int tid = threadIdx.x;
  const int w = tid >> 6, lane = tid & 63;
  const int pg = w >> 1, ch = w & 1;
  const int q = lane >> 4, c = lane & 15;
  const int blk = blockIdx.x;
  const int b = blk >> 3;             // batch index
  const int hwb = (blk & 7) << 7;     // hw base (128 pts/block)

  cnorm_s[tid] = cnorm[tid];
  cnorm_s[tid + 256] = cnorm[tid + 256];
  cnorm_s[tid + 512] = cnorm[tid + 512];
  cnorm_s[tid + 768] = cnorm[tid + 768];

  // ---- stage both 64-pt tiles (bf16, swizzled, conflict-free b128 writes) ----
  const int jb = w * 8;               // this thread's 8 feature-octets
#pragma unroll 1
  for (int t = 0; t < 2; ++t) {
    unsigned short* tileu = (unsigned short*)&dbuf[t][0];  // 64 rows x 512B
#pragma unroll 4
    for (int jj = 0; jj < 8; ++jj) {
      int j = jb + jj;                // features 8j..8j+7
      short8 v;
#pragma unroll
      for (int e = 0; e < 8; ++e) {
        float f = lat[((size_t)(b * D_ + j * 8 + e)) * HW_ + hwb + t * 64 + lane];
        v[e] = (short)f2bf(f);
      }
      *(short8*)&tileu[lane * 256 + ((j * 8) ^ ((lane & 15) << 4))] = v;
    }
  }
  __syncthreads();

  // ---- extract B-frags (wave pair 2pg,2pg+1 both read tile pg) ----
  short8 bfrag[4][8];
  float fn[4];
  {
    unsigned short* tileu = (unsigned short*)&dbuf[pg][0];
#pragma unroll
    for (int pf = 0; pf < 4; ++pf) {
      int row = pf * 16 + c;
#pragma unroll
      for (int kk = 0; kk < 8; ++kk) {
        int s = (kk << 2) | q;
        bfrag[pf][kk] =
            *(const short8*)&tileu[row * 256 + ((s * 8) ^ ((row & 15) << 4))];
      }
      float a = 0.f;
#pragma unroll
      for (int kk = 0; kk < 8; ++kk)
#pragma unroll
        for (int e = 0; e < 8; ++e) {
          float f = bf2f((unsigned short)bfrag[pf][kk][e]);
          a += f * f;
        }
      fn[pf] = a;
    }
#pragma unroll
    for (int pf = 0; pf < 4; ++pf) {
      fn[pf] += __shfl_xor(fn[pf], 16, 64);
      fn[pf] += __shfl_xor(fn[pf], 32, 64);
    }
  }
  __syncthreads();  // tiles consumed; dbuf free for codebook stream

  // ---- stream 16 codebook chunks (32KB, double-buffered) ----
  float runD[4];
  int runI[4];
#pragma unroll
  for (int pf = 0; pf < 4; ++pf) { runD[pf] = 3.0e38f; runI[pf] = 0x7fffffff; }

#pragma unroll
  for (int r = 0; r < 8; ++r)
    async16(&dbuf[0][r * 256 + tid], cbimg + (r * 256 + tid));
  __syncthreads();

  int buf = 0;
#pragma unroll 1
  for (int chunk = 0; chunk < 16; ++chunk) {
    if (chunk < 15) {
#pragma unroll
      for (int r = 0; r < 8; ++r)
        async16(&dbuf[buf ^ 1][r * 256 + tid],
                cbimg + ((chunk + 1) * 2048 + r * 256 + tid));
    }
    float4v acc[2][4];
#pragma unroll
    for (int af = 0; af < 2; ++af) {
      float4v cn = *(const float4v*)&cnorm_s[chunk * 64 + ch * 32 + af * 16 + q * 4];
#pragma unroll
      for (int pf = 0; pf < 4; ++pf) acc[af][pf] = cn;
    }
#pragma unroll
    for (int kk = 0; kk < 8; ++kk) {
      short8 a[2];
#pragma unroll
      for (int af = 0; af < 2; ++af) {
        int row = ch * 32 + af * 16 + c;
        a[af] = dbuf[buf][row * 32 + (((kk << 2) | q) ^ (c << 1))];
      }
#pragma unroll
      for (int af = 0; af < 2; ++af)
#pragma unroll
        for (int pf = 0; pf < 4; ++pf)
          acc[af][pf] = __builtin_amdgcn_mfma_f32_16x16x32_bf16(
              a[af], bfrag[pf][kk], acc[af][pf], 0, 0, 0);
    }
    // lane-local scan (ascending code index; strict < = first occurrence)
#pragma unroll
    for (int pf = 0; pf < 4; ++pf)
#pragma unroll
      for (int af = 0; af < 2; ++af) {
        int cb0 = chunk * 64 + ch * 32 + af * 16 + q * 4;
#pragma unroll
        for (int r = 0; r < 4; ++r) {
          float dv = acc[af][pf][r];
          if (dv < runD[pf]) { runD[pf] = dv; runI[pf] = cb0 + r; }
        }
      }
    __syncthreads();
    buf ^= 1;
  }

  // ---- deferred butterfly + cross-wave merge; idx to LDS; loss partial ----
#pragma unroll
  for (int pf = 0; pf < 4; ++pf) {
#pragma unroll
    for (int di = 16; di < 64; di <<= 1) {
      float od = __shfl_xor(runD[pf], di, 64);
      int oi = __shfl_xor(runI[pf], di, 64);
      if (od < runD[pf] || (od == runD[pf] && oi < runI[pf])) {
        runD[pf] = od; runI[pf] = oi;
      }
    }
  }
  float selD = q == 0 ? runD[0] : q == 1 ? runD[1] : q == 2 ? runD[2] : runD[3];
  int selI = q == 0 ? runI[0] : q == 1 ? runI[1] : q == 2 ? runI[2] : runI[3];
  float selF = q == 0 ? fn[0] : q == 1 ? fn[1] : q == 2 ? fn[2] : fn[3];
  int p = pg * 64 + q * 16 + c;
  if (ch == 1) { mergeD[p] = selD; mergeI[p] = selI; }
  __syncthreads();
  if (ch == 0) {
    float od = mergeD[p];
    int oi = mergeI[p];
    if (od < selD || (od == selD && oi < selI)) { selD = od; selI = oi; }
    idx_s[p] = selI;
    float lv = selD + selF;  // ||f - c_best||^2
#pragma unroll
    for (int off = 1; off < 64; off <<= 1) lv += __shfl_xor(lv, off, 64);
    if (lane == 0) part[blk * 2 + pg] = lv;
  }
  __syncthreads();

  // ---- cooperative gather: wave reads whole cb rows (1KB float4 instrs) ----
  // into bf16 swizzled tiles, then conflict-free b128 reads + coalesced stores.
#pragma unroll 1
  for (int st = 0; st < 2; ++st) {
    unsigned short* tileu = (unsigned short*)&dbuf[st][0];
#pragma unroll 4
    for (int rp = 0; rp < 16; ++rp) {
      int row = rp * 4 + w;
      int gidx = idx_s[st * 64 + row];
      float4v cv = ((const float4v*)(cb + (size_t)gidx * D_))[lane];
      short4v sv;
#pragma unroll
      for (int i = 0; i < 4; ++i) sv[i] = (short)f2bf(cv[i]);
      *(short4v*)&tileu[row * 256 + ((lane * 4) ^ ((row & 15) << 4))] = sv;
    }
  }
  __syncthreads();
#pragma unroll 1
  for (int st = 0; st < 2; ++st) {
    unsigned short* tileu = (unsigned short*)&dbuf[st][0];
#pragma unroll
    for (int jo = 0; jo < 8; ++jo) {
      int j = w * 8 + jo;             // feature octet
      short8 v = *(const short8*)&tileu[lane * 256 + ((j * 8) ^ ((lane & 15) << 4))];
#pragma unroll
      for (int e = 0; e < 8; ++e)
        out[((size_t)(b * D_ + j * 8 + e)) * HW_ + hwb + st * 64 + lane] =
            bf2f((unsigned short)v[e]);
    }
  }
}

// ---- finalize: loss = 1.25 * mean (1024 partials) ----
__global__ __launch_bounds__(256) void vq_fin(const float* __restrict__ part,
                                              float* __restrict__ outs) {
  int t = threadIdx.x;
  float s = part[t] + part[t + 256] + part[t + 512] + part[t + 768];
#pragma unroll
  for (int off = 1; off < 64; off <<= 1) s += __shfl_xor(s, off, 64);
  __shared__ float w4[4];
  if ((t & 63) == 0) w4[t >> 6] = s;
  __syncthreads();
  if (t == 0) *outs = (w4[0] + w4[1] + w4[2] + w4[3]) * (1.25f / 16777216.0f);
}

extern "C" void kernel_launch(void* const* d_in, const int* in_sizes, int n_in,
                              void* d_out, int out_size, void* d_ws, size_t ws_size,
                              hipStream_t stream) {
  const float* lat = (const float*)d_in[0];
  const float* cb = (const float*)d_in[1];
  float* out = (float*)d_out;
  char* ws = (char*)d_ws;
  unsigned short* cbimg = (unsigned short*)ws;   // 512 KB (bf16 -2c image)
  float* cnorm = (float*)(ws + 524288);          // 4 KB
  float* partial = (float*)(ws + 528384);        // 4 KB (1024 floats)

  vq_prep<<<1024, 256, 0, stream>>>(cb, cbimg, cnorm);
  vq_main<<<512, 256, 0, stream>>>(lat, (const short8*)cbimg, cnorm, cb, out,
                                   partial);
  vq_fin<<<1, 256, 0, stream>>>(partial, out + 16777216);
}